// Round 14
// baseline (404.355 us; speedup 1.0000x reference)
//
#include <hip/hip_runtime.h>

#define N_GRID 144
#define INV_DX 128.0f
#define NBINS 32768          // 32 x 32 x 32 bins of 4^3 cells
#define SCAN_THREADS 1024
#define PER_THREAD 32        // 1024 * 32 = 32768
#define KP 8                 // particles per thread in streaming passes

typedef unsigned long long u64;

__device__ __forceinline__ int bin_of(float px, float py, float pz) {
    int bx = (int)(px * INV_DX);   // 0..127
    int by = (int)(py * INV_DX);
    int bz = (int)(pz * INV_DX);
    return ((bx >> 2) << 10) | ((by >> 2) << 5) | (bz >> 2);
}

// Pass 0: bin16[i] = bin index (coalesced, no atomics). Feeds hist8 only.
__global__ void __launch_bounds__(256) binify_kernel(
    const float* __restrict__ pos, unsigned short* __restrict__ bin16, int n)
{
    int base = blockIdx.x * (blockDim.x * KP) + threadIdx.x;
#pragma unroll
    for (int k = 0; k < KP; ++k) {
        int p = base + k * 256;
        if (p < n) {
            bin16[p] = (unsigned short)bin_of(pos[3 * p + 0], pos[3 * p + 1], pos[3 * p + 2]);
        }
    }
}

// Pass 1: octant-filtered histogram from bin16. Atomics hit an XCD-private
// 16KB hist slice (bin>>12 = x-octant) under round-robin dispatch.
__global__ void __launch_bounds__(256) hist8_kernel(
    const unsigned short* __restrict__ bin16, unsigned int* __restrict__ hist, int n)
{
    int owner = blockIdx.x & 7;
    int chunk = blockIdx.x >> 3;
    int base = chunk * (256 * KP) + threadIdx.x;
    int bn[KP], ok[KP];
#pragma unroll
    for (int k = 0; k < KP; ++k) {
        int p = base + k * 256;
        ok[k] = (p < n);
        bn[k] = bin16[ok[k] ? p : 0];
        ok[k] = ok[k] && ((bn[k] >> 12) == owner);
    }
#pragma unroll
    for (int k = 0; k < KP; ++k) {
        if (ok[k]) atomicAdd(&hist[bn[k]], 1u);
    }
}

__global__ void __launch_bounds__(SCAN_THREADS) scan_kernel(
    const unsigned int* __restrict__ hist, unsigned int* __restrict__ offs)
{
    __shared__ unsigned int partial[SCAN_THREADS];
    int t = threadIdx.x;
    unsigned int local[PER_THREAD];
    unsigned int s = 0;
    int base = t * PER_THREAD;
#pragma unroll
    for (int k = 0; k < PER_THREAD; ++k) {
        local[k] = s;
        s += hist[base + k];
    }
    partial[t] = s;
    __syncthreads();
    for (int d = 1; d < SCAN_THREADS; d <<= 1) {
        unsigned int v = (t >= d) ? partial[t - d] : 0u;
        __syncthreads();
        partial[t] += v;
        __syncthreads();
    }
    unsigned int chunk_excl = (t == 0) ? 0u : partial[t - 1];
#pragma unroll
    for (int k = 0; k < PER_THREAD; ++k)
        offs[base + k] = chunk_excl + local[k];
}

// Pass 2: octant-filtered scatter with PACKED u64 payload:
// [idx:22 | rx:2 | ry:2 | rz:2 | lx:12 | ly:12 | lz:12]
// Dense coalesced pos reads, inline bin, XCD-local atomics; 8B stores halve
// the partial-line write (and RFO read) traffic vs float4.
__global__ void __launch_bounds__(256) scatter8_kernel(
    const float* __restrict__ pos, u64* __restrict__ sorted,
    unsigned int* __restrict__ offs, int n)
{
    int owner = blockIdx.x & 7;
    int chunk = blockIdx.x >> 3;
    int base = chunk * (256 * KP) + threadIdx.x;
    u64 ent[KP];
    int ok[KP], bn[KP];
#pragma unroll
    for (int k = 0; k < KP; ++k) {
        int p = base + k * 256;
        ok[k] = (p < n);
        int q = ok[k] ? p : 0;
        float px = pos[3 * q + 0];
        float py = pos[3 * q + 1];
        float pz = pos[3 * q + 2];
        float nx = px * INV_DX, ny = py * INV_DX, nz = pz * INV_DX;
        int bx = (int)nx, by = (int)ny, bz = (int)nz;
        float lx = nx - (float)bx, ly = ny - (float)by, lz = nz - (float)bz;
        unsigned int lxq = (unsigned int)(lx * 4096.0f);
        unsigned int lyq = (unsigned int)(ly * 4096.0f);
        unsigned int lzq = (unsigned int)(lz * 4096.0f);
        bn[k] = ((bx >> 2) << 10) | ((by >> 2) << 5) | (bz >> 2);
        ent[k] = ((u64)(unsigned int)q << 42)
               | ((u64)(bx & 3) << 40) | ((u64)(by & 3) << 38) | ((u64)(bz & 3) << 36)
               | ((u64)lxq << 24) | ((u64)lyq << 12) | (u64)lzq;
        ok[k] = ok[k] && ((bn[k] >> 12) == owner);
    }
    unsigned int off[KP];
#pragma unroll
    for (int k = 0; k < KP; ++k) {
        if (ok[k]) off[k] = atomicAdd(&offs[bn[k]], 1u);
    }
#pragma unroll
    for (int k = 0; k < KP; ++k) {
        if (ok[k]) sorted[off[k]] = ent[k];
    }
}

// Pass 3: bin-centric gather from packed entries. One 128-thread block per
// bin; 6x6x6-node stencil (648 floats) in LDS; weights recomputed from the
// centered 12-bit fractions. pos is not read at all.
__global__ void __launch_bounds__(128) gather_bin_kernel(
    const float* __restrict__ grid,
    const u64* __restrict__ sorted,
    const unsigned int* __restrict__ offs_end,
    const unsigned int* __restrict__ hist,
    float* __restrict__ out)
{
    int b = (blockIdx.x & 7) * 4096 + (blockIdx.x >> 3);   // bijective, 32768=8*4096

    unsigned int end = offs_end[b];
    unsigned int cnt = hist[b];
    if (cnt == 0) return;
    unsigned int start = end - cnt;

    int obx = 4 * (b >> 10);
    int oby = 4 * ((b >> 5) & 31);
    int obz = 4 * (b & 31);

    const int s1 = N_GRID * 3;
    const int s0 = N_GRID * N_GRID * 3;

    __shared__ float R[648];          // [6][6][18]
    const float* gorig = grid + (long)obx * s0 + oby * s1 + obz * 3;
    int tid = threadIdx.x;
#pragma unroll
    for (int f = tid; f < 648; f += 128) {
        int row = f / 18;
        int zz = f - row * 18;
        R[f] = gorig[(row / 6) * s0 + (row % 6) * s1 + zz];
    }
    __syncthreads();

    const float qs = 1.0f / 4096.0f;
    for (unsigned int j = start + tid; j < end; j += 128) {
        u64 e = sorted[j];
        int lzq = (int)(e & 4095u);
        int lyq = (int)((e >> 12) & 4095u);
        int lxq = (int)((e >> 24) & 4095u);
        int rz = (int)((e >> 36) & 3u);
        int ry = (int)((e >> 38) & 3u);
        int rx = (int)((e >> 40) & 3u);
        int idx = (int)(e >> 42);

        float lx = ((float)lxq + 0.5f) * qs;
        float ly = ((float)lyq + 0.5f) * qs;
        float lz = ((float)lzq + 0.5f) * qs;

        float wx[3], wy[3], wz[3];
        wx[0] = 0.5f * (1.0f - lx) * (1.0f - lx);
        wx[1] = 0.75f - (0.5f - lx) * (0.5f - lx);
        wx[2] = 0.5f * lx * lx;
        wy[0] = 0.5f * (1.0f - ly) * (1.0f - ly);
        wy[1] = 0.75f - (0.5f - ly) * (0.5f - ly);
        wy[2] = 0.5f * ly * ly;
        wz[0] = 0.5f * (1.0f - lz) * (1.0f - lz);
        wz[1] = 0.75f - (0.5f - lz) * (0.5f - lz);
        wz[2] = 0.5f * lz * lz;

        float ox = 0.0f, oy = 0.0f, oz = 0.0f;
#pragma unroll
        for (int a = 0; a < 3; ++a) {
#pragma unroll
            for (int bb = 0; bb < 3; ++bb) {
                const float* pp = &R[((rx + a) * 6 + (ry + bb)) * 18 + rz * 3];
                float wab = wx[a] * wy[bb];
                float w0 = wab * wz[0];
                float w1 = wab * wz[1];
                float w2 = wab * wz[2];
                ox += w0 * pp[0] + w1 * pp[3] + w2 * pp[6];
                oy += w0 * pp[1] + w1 * pp[4] + w2 * pp[7];
                oz += w0 * pp[2] + w1 * pp[5] + w2 * pp[8];
            }
        }

        out[3 * idx + 0] = ox;
        out[3 * idx + 1] = oy;
        out[3 * idx + 2] = oz;
    }
}

// Fallback: naive per-particle gather
__global__ void __launch_bounds__(256) g2p_naive_kernel(
    const float* __restrict__ grid, const float* __restrict__ pos,
    float* __restrict__ out, int n)
{
    int i = blockIdx.x * blockDim.x + threadIdx.x;
    if (i >= n) return;
    float px = pos[3 * i + 0], py = pos[3 * i + 1], pz = pos[3 * i + 2];
    float nx = px * INV_DX, ny = py * INV_DX, nz = pz * INV_DX;
    int bx = (int)nx, by = (int)ny, bz = (int)nz;
    float lx = nx - bx, ly = ny - by, lz = nz - bz;
    float wx[3], wy[3], wz[3];
    wx[0] = 0.5f * (1.0f - lx) * (1.0f - lx);
    wx[1] = 0.75f - (0.5f - lx) * (0.5f - lx);
    wx[2] = 0.5f * lx * lx;
    wy[0] = 0.5f * (1.0f - ly) * (1.0f - ly);
    wy[1] = 0.75f - (0.5f - ly) * (0.5f - ly);
    wy[2] = 0.5f * ly * ly;
    wz[0] = 0.5f * (1.0f - lz) * (1.0f - lz);
    wz[1] = 0.75f - (0.5f - lz) * (0.5f - lz);
    wz[2] = 0.5f * lz * lz;
    const int s1 = N_GRID * 3, s0 = N_GRID * N_GRID * 3;
    const float* gbase = grid + (long)bx * s0 + by * s1 + bz * 3;
    float ox = 0, oy = 0, oz = 0;
#pragma unroll
    for (int a = 0; a < 3; ++a)
#pragma unroll
        for (int b = 0; b < 3; ++b) {
            const float* pp = gbase + a * s0 + b * s1;
            float wab = wx[a] * wy[b];
            float w0 = wab * wz[0], w1 = wab * wz[1], w2 = wab * wz[2];
            ox += w0 * pp[0] + w1 * pp[3] + w2 * pp[6];
            oy += w0 * pp[1] + w1 * pp[4] + w2 * pp[7];
            oz += w0 * pp[2] + w1 * pp[5] + w2 * pp[8];
        }
    out[3 * i + 0] = ox;
    out[3 * i + 1] = oy;
    out[3 * i + 2] = oz;
}

extern "C" void kernel_launch(void* const* d_in, const int* in_sizes, int n_in,
                              void* d_out, int out_size, void* d_ws, size_t ws_size,
                              hipStream_t stream) {
    const float* grid = (const float*)d_in[0];
    const float* pos  = (const float*)d_in[1];
    float* out        = (float*)d_out;
    int n = in_sizes[1] / 3;

    int block = 256;
    int blocks = (n + block - 1) / block;
    int blocksK = (n + block * KP - 1) / (block * KP);

    // ws layout: [0,128K) hist | [128K,256K) offs | [256K, 256K+2n) bin16 |
    //            [align256, +8n) sorted (u64)
    size_t bin_off = 256u << 10;
    size_t sorted_off = (bin_off + (size_t)n * 2 + 255) & ~(size_t)255;
    size_t need = sorted_off + (size_t)n * sizeof(u64);

    if (ws_size < need || n > (1 << 22)) {
        g2p_naive_kernel<<<blocks, block, 0, stream>>>(grid, pos, out, n);
        return;
    }

    unsigned int* hist = (unsigned int*)d_ws;
    unsigned int* offs = hist + NBINS;
    unsigned short* bin16 = (unsigned short*)((char*)d_ws + bin_off);
    u64* sorted = (u64*)((char*)d_ws + sorted_off);

    hipMemsetAsync(hist, 0, NBINS * sizeof(unsigned int), stream);
    binify_kernel<<<blocksK, block, 0, stream>>>(pos, bin16, n);
    hist8_kernel<<<blocksK * 8, block, 0, stream>>>(bin16, hist, n);
    scan_kernel<<<1, SCAN_THREADS, 0, stream>>>(hist, offs);
    scatter8_kernel<<<blocksK * 8, block, 0, stream>>>(pos, sorted, offs, n);
    gather_bin_kernel<<<NBINS, 128, 0, stream>>>(grid, sorted, offs, hist, out);
}

// Round 15
// 236.797 us; speedup vs baseline: 1.7076x; 1.7076x over previous
//
#include <hip/hip_runtime.h>

#define N_GRID 144
#define INV_DX 128.0f
#define NBINS 32768          // 32 x 32 x 32 bins of 4^3 cells
#define CAP 192              // slots per bin: mean 122, +6.4 sigma
#define KP 8                 // particles per thread in scatter
#define OVF_MAX 65536

typedef unsigned long long u64;

// ---- packing helpers (shared by scatter and both gathers; bit-identical) ----
__device__ __forceinline__ u64 pack_particle(int p, float px, float py, float pz, int* bn)
{
    float nx = px * INV_DX, ny = py * INV_DX, nz = pz * INV_DX;
    int bx = (int)nx, by = (int)ny, bz = (int)nz;
    float lx = nx - (float)bx, ly = ny - (float)by, lz = nz - (float)bz;
    unsigned int lxq = (unsigned int)(lx * 4096.0f);
    unsigned int lyq = (unsigned int)(ly * 4096.0f);
    unsigned int lzq = (unsigned int)(lz * 4096.0f);
    *bn = ((bx >> 2) << 10) | ((by >> 2) << 5) | (bz >> 2);
    return ((u64)(unsigned int)p << 42)
         | ((u64)(bx & 3) << 40) | ((u64)(by & 3) << 38) | ((u64)(bz & 3) << 36)
         | ((u64)lxq << 24) | ((u64)lyq << 12) | (u64)lzq;
}

__device__ __forceinline__ void eval_packed(
    u64 e, const float* __restrict__ R, int ldsbase_is_6x6x18,
    float* ox, float* oy, float* oz, int* idx)
{
    const float qs = 1.0f / 4096.0f;
    int lzq = (int)(e & 4095u);
    int lyq = (int)((e >> 12) & 4095u);
    int lxq = (int)((e >> 24) & 4095u);
    int rz = (int)((e >> 36) & 3u);
    int ry = (int)((e >> 38) & 3u);
    int rx = (int)((e >> 40) & 3u);
    *idx = (int)(e >> 42);

    float lx = ((float)lxq + 0.5f) * qs;
    float ly = ((float)lyq + 0.5f) * qs;
    float lz = ((float)lzq + 0.5f) * qs;

    float wx[3], wy[3], wz[3];
    wx[0] = 0.5f * (1.0f - lx) * (1.0f - lx);
    wx[1] = 0.75f - (0.5f - lx) * (0.5f - lx);
    wx[2] = 0.5f * lx * lx;
    wy[0] = 0.5f * (1.0f - ly) * (1.0f - ly);
    wy[1] = 0.75f - (0.5f - ly) * (0.5f - ly);
    wy[2] = 0.5f * ly * ly;
    wz[0] = 0.5f * (1.0f - lz) * (1.0f - lz);
    wz[1] = 0.75f - (0.5f - lz) * (0.5f - lz);
    wz[2] = 0.5f * lz * lz;

    float sx = 0.0f, sy = 0.0f, sz = 0.0f;
#pragma unroll
    for (int a = 0; a < 3; ++a) {
#pragma unroll
        for (int bb = 0; bb < 3; ++bb) {
            const float* pp = &R[((rx + a) * 6 + (ry + bb)) * 18 + rz * 3];
            float wab = wx[a] * wy[bb];
            float w0 = wab * wz[0];
            float w1 = wab * wz[1];
            float w2 = wab * wz[2];
            sx += w0 * pp[0] + w1 * pp[3] + w2 * pp[6];
            sy += w0 * pp[1] + w1 * pp[4] + w2 * pp[7];
            sz += w0 * pp[2] + w1 * pp[5] + w2 * pp[8];
        }
    }
    *ox = sx; *oy = sy; *oz = sz;
}

// ---- Pass 1 (the only sort pass): octant-filtered slot-slab scatter ----
__global__ void __launch_bounds__(256) scatter_slab_kernel(
    const float* __restrict__ pos, u64* __restrict__ slab,
    unsigned int* __restrict__ cnt,
    unsigned int* __restrict__ ovf_list, unsigned int* __restrict__ ovf_cnt, int n)
{
    int owner = blockIdx.x & 7;
    int chunk = blockIdx.x >> 3;
    int base = chunk * (256 * KP) + threadIdx.x;
    u64 ent[KP];
    int ok[KP], bn[KP];
#pragma unroll
    for (int k = 0; k < KP; ++k) {
        int p = base + k * 256;
        ok[k] = (p < n);
        int q = ok[k] ? p : 0;
        ent[k] = pack_particle(q, pos[3 * q + 0], pos[3 * q + 1], pos[3 * q + 2], &bn[k]);
        ok[k] = ok[k] && ((bn[k] >> 12) == owner);   // x-octant filter -> XCD-local atomics
    }
    unsigned int r[KP];
#pragma unroll
    for (int k = 0; k < KP; ++k) {
        if (ok[k]) r[k] = atomicAdd(&cnt[bn[k]], 1u);
    }
#pragma unroll
    for (int k = 0; k < KP; ++k) {
        if (ok[k]) {
            if (r[k] < CAP) {
                slab[(size_t)bn[k] * CAP + r[k]] = ent[k];
            } else {
                unsigned int o = atomicAdd(ovf_cnt, 1u);
                if (o < OVF_MAX) ovf_list[o] = (unsigned int)(base + k * 256);
            }
        }
    }
}

// ---- Pass 2: bin-centric LDS-staged gather over the slab ----
__global__ void __launch_bounds__(128) gather_bin_kernel(
    const float* __restrict__ grid,
    const u64* __restrict__ slab,
    const unsigned int* __restrict__ cnt,
    float* __restrict__ out)
{
    int b = (blockIdx.x & 7) * 4096 + (blockIdx.x >> 3);   // bijective, 32768=8*4096

    unsigned int c = cnt[b];
    if (c == 0) return;
    if (c > CAP) c = CAP;

    int obx = 4 * (b >> 10);
    int oby = 4 * ((b >> 5) & 31);
    int obz = 4 * (b & 31);

    const int s1 = N_GRID * 3;
    const int s0 = N_GRID * N_GRID * 3;

    __shared__ float R[648];          // [6][6][18]
    const float* gorig = grid + (long)obx * s0 + oby * s1 + obz * 3;
    int tid = threadIdx.x;
#pragma unroll
    for (int f = tid; f < 648; f += 128) {
        int row = f / 18;
        int zz = f - row * 18;
        R[f] = gorig[(row / 6) * s0 + (row % 6) * s1 + zz];
    }
    __syncthreads();

    const u64* sb = slab + (size_t)b * CAP;
    for (unsigned int j = tid; j < c; j += 128) {
        u64 e = sb[j];
        float ox, oy, oz;
        int idx;
        eval_packed(e, R, 0, &ox, &oy, &oz, &idx);
        out[3 * idx + 0] = ox;
        out[3 * idx + 1] = oy;
        out[3 * idx + 2] = oz;
    }
}

// ---- Pass 3: overflow particles (expected count ~0); same quantization ----
__global__ void __launch_bounds__(256) gather_ovf_kernel(
    const float* __restrict__ grid, const float* __restrict__ pos,
    const unsigned int* __restrict__ ovf_list, const unsigned int* __restrict__ ovf_cnt,
    float* __restrict__ out)
{
    unsigned int c = *ovf_cnt;
    if (c > OVF_MAX) c = OVF_MAX;
    const int s1 = N_GRID * 3;
    const int s0 = N_GRID * N_GRID * 3;
    const float qs = 1.0f / 4096.0f;
    for (unsigned int s = blockIdx.x * blockDim.x + threadIdx.x; s < c;
         s += gridDim.x * blockDim.x) {
        int p = (int)ovf_list[s];
        int bn;
        u64 e = pack_particle(p, pos[3 * p + 0], pos[3 * p + 1], pos[3 * p + 2], &bn);
        int obx = 4 * (bn >> 10);
        int oby = 4 * ((bn >> 5) & 31);
        int obz = 4 * (bn & 31);

        int lzq = (int)(e & 4095u);
        int lyq = (int)((e >> 12) & 4095u);
        int lxq = (int)((e >> 24) & 4095u);
        int rz = (int)((e >> 36) & 3u);
        int ry = (int)((e >> 38) & 3u);
        int rx = (int)((e >> 40) & 3u);
        int idx = (int)(e >> 42);

        float lx = ((float)lxq + 0.5f) * qs;
        float ly = ((float)lyq + 0.5f) * qs;
        float lz = ((float)lzq + 0.5f) * qs;

        float wx[3], wy[3], wz[3];
        wx[0] = 0.5f * (1.0f - lx) * (1.0f - lx);
        wx[1] = 0.75f - (0.5f - lx) * (0.5f - lx);
        wx[2] = 0.5f * lx * lx;
        wy[0] = 0.5f * (1.0f - ly) * (1.0f - ly);
        wy[1] = 0.75f - (0.5f - ly) * (0.5f - ly);
        wy[2] = 0.5f * ly * ly;
        wz[0] = 0.5f * (1.0f - lz) * (1.0f - lz);
        wz[1] = 0.75f - (0.5f - lz) * (0.5f - lz);
        wz[2] = 0.5f * lz * lz;

        const float* gbase = grid + (long)(obx + rx) * s0 + (oby + ry) * s1 + (obz + rz) * 3;
        float ox = 0, oy = 0, oz = 0;
#pragma unroll
        for (int a = 0; a < 3; ++a)
#pragma unroll
            for (int bb = 0; bb < 3; ++bb) {
                const float* pp = gbase + a * s0 + bb * s1;
                float wab = wx[a] * wy[bb];
                float w0 = wab * wz[0], w1 = wab * wz[1], w2 = wab * wz[2];
                ox += w0 * pp[0] + w1 * pp[3] + w2 * pp[6];
                oy += w0 * pp[1] + w1 * pp[4] + w2 * pp[7];
                oz += w0 * pp[2] + w1 * pp[5] + w2 * pp[8];
            }
        out[3 * idx + 0] = ox;
        out[3 * idx + 1] = oy;
        out[3 * idx + 2] = oz;
    }
}

// Fallback: naive per-particle gather
__global__ void __launch_bounds__(256) g2p_naive_kernel(
    const float* __restrict__ grid, const float* __restrict__ pos,
    float* __restrict__ out, int n)
{
    int i = blockIdx.x * blockDim.x + threadIdx.x;
    if (i >= n) return;
    float px = pos[3 * i + 0], py = pos[3 * i + 1], pz = pos[3 * i + 2];
    float nx = px * INV_DX, ny = py * INV_DX, nz = pz * INV_DX;
    int bx = (int)nx, by = (int)ny, bz = (int)nz;
    float lx = nx - bx, ly = ny - by, lz = nz - bz;
    float wx[3], wy[3], wz[3];
    wx[0] = 0.5f * (1.0f - lx) * (1.0f - lx);
    wx[1] = 0.75f - (0.5f - lx) * (0.5f - lx);
    wx[2] = 0.5f * lx * lx;
    wy[0] = 0.5f * (1.0f - ly) * (1.0f - ly);
    wy[1] = 0.75f - (0.5f - ly) * (0.5f - ly);
    wy[2] = 0.5f * ly * ly;
    wz[0] = 0.5f * (1.0f - lz) * (1.0f - lz);
    wz[1] = 0.75f - (0.5f - lz) * (0.5f - lz);
    wz[2] = 0.5f * lz * lz;
    const int s1 = N_GRID * 3, s0 = N_GRID * N_GRID * 3;
    const float* gbase = grid + (long)bx * s0 + by * s1 + bz * 3;
    float ox = 0, oy = 0, oz = 0;
#pragma unroll
    for (int a = 0; a < 3; ++a)
#pragma unroll
        for (int b = 0; b < 3; ++b) {
            const float* pp = gbase + a * s0 + b * s1;
            float wab = wx[a] * wy[b];
            float w0 = wab * wz[0], w1 = wab * wz[1], w2 = wab * wz[2];
            ox += w0 * pp[0] + w1 * pp[3] + w2 * pp[6];
            oy += w0 * pp[1] + w1 * pp[4] + w2 * pp[7];
            oz += w0 * pp[2] + w1 * pp[5] + w2 * pp[8];
        }
    out[3 * i + 0] = ox;
    out[3 * i + 1] = oy;
    out[3 * i + 2] = oz;
}

extern "C" void kernel_launch(void* const* d_in, const int* in_sizes, int n_in,
                              void* d_out, int out_size, void* d_ws, size_t ws_size,
                              hipStream_t stream) {
    const float* grid = (const float*)d_in[0];
    const float* pos  = (const float*)d_in[1];
    float* out        = (float*)d_out;
    int n = in_sizes[1] / 3;

    int block = 256;
    int blocks = (n + block - 1) / block;
    int blocksK = (n + block * KP - 1) / (block * KP);

    // ws layout: [0,128K) cnt | [128K,128K+4) ovf_cnt | [132K, +256K) ovf_list |
    //            [align256, +NBINS*CAP*8) slab
    size_t ovfcnt_off = 128u << 10;
    size_t ovflist_off = 132u << 10;
    size_t slab_off = (ovflist_off + (size_t)OVF_MAX * 4 + 255) & ~(size_t)255;
    size_t slab_bytes = (size_t)NBINS * CAP * sizeof(u64);   // 50.3 MB
    size_t need = slab_off + slab_bytes;

    if (ws_size < need || n > (1 << 22)) {
        g2p_naive_kernel<<<blocks, block, 0, stream>>>(grid, pos, out, n);
        return;
    }

    unsigned int* cnt = (unsigned int*)d_ws;
    unsigned int* ovf_cnt = (unsigned int*)((char*)d_ws + ovfcnt_off);
    unsigned int* ovf_list = (unsigned int*)((char*)d_ws + ovflist_off);
    u64* slab = (u64*)((char*)d_ws + slab_off);

    hipMemsetAsync(cnt, 0, NBINS * sizeof(unsigned int), stream);
    hipMemsetAsync(ovf_cnt, 0, sizeof(unsigned int), stream);
    scatter_slab_kernel<<<blocksK * 8, block, 0, stream>>>(pos, slab, cnt, ovf_list, ovf_cnt, n);
    gather_bin_kernel<<<NBINS, 128, 0, stream>>>(grid, slab, cnt, out);
    gather_ovf_kernel<<<16, block, 0, stream>>>(grid, pos, ovf_list, ovf_cnt, out);
}

// Round 16
// 151.276 us; speedup vs baseline: 2.6730x; 1.5653x over previous
//
#include <hip/hip_runtime.h>

#define N_GRID 144
#define INV_DX 128.0f
#define NBINS 32768          // 32^3 bins of 4^3 cells; bin = X<<10|Y<<5|Z
#define CAP 192              // fine slab slots per bin (mean 122, +6.4 sigma)
#define NCOARSE 512          // coarse bucket = bin >> 6
#define CAP_C 8448           // coarse slots per bucket (mean 7812, +7 sigma)
#define CAPP 16              // ccnt padding (one 64B line per counter)
#define TILE_A 4096          // particles per phase-A block
#define OVF_MAX 65536

typedef unsigned long long u64;

__device__ __forceinline__ int bin_of(float px, float py, float pz) {
    int bx = (int)(px * INV_DX);
    int by = (int)(py * INV_DX);
    int bz = (int)(pz * INV_DX);
    return ((bx >> 2) << 10) | ((by >> 2) << 5) | (bz >> 2);
}

// packed entry: [idx:22 | rx:2 | ry:2 | rz:2 | lx:12 | ly:12 | lz:12]
__device__ __forceinline__ u64 pack_particle(int p, float px, float py, float pz, int* bn)
{
    float nx = px * INV_DX, ny = py * INV_DX, nz = pz * INV_DX;
    int bx = (int)nx, by = (int)ny, bz = (int)nz;
    float lx = nx - (float)bx, ly = ny - (float)by, lz = nz - (float)bz;
    unsigned int lxq = (unsigned int)(lx * 4096.0f);
    unsigned int lyq = (unsigned int)(ly * 4096.0f);
    unsigned int lzq = (unsigned int)(lz * 4096.0f);
    *bn = ((bx >> 2) << 10) | ((by >> 2) << 5) | (bz >> 2);
    return ((u64)(unsigned int)p << 42)
         | ((u64)(bx & 3) << 40) | ((u64)(by & 3) << 38) | ((u64)(bz & 3) << 36)
         | ((u64)lxq << 24) | ((u64)lyq << 12) | (u64)lzq;
}

// ---- Phase A: coarse split. pos read once; all global writes run-contiguous ----
__global__ void __launch_bounds__(256) coarse_split_kernel(
    const float* __restrict__ pos,
    u64* __restrict__ coarse, unsigned char* __restrict__ fine8,
    unsigned int* __restrict__ ccnt,          // padded stride CAPP, zeroed
    unsigned int* __restrict__ ovf_list, unsigned int* __restrict__ ovf_cnt, int n)
{
    __shared__ u64 stage[TILE_A];             // 32 KB
    __shared__ unsigned short bstage[TILE_A]; // 8 KB
    __shared__ unsigned int hist[NCOARSE];    // 2 KB
    __shared__ unsigned int lstart[NCOARSE];  // 2 KB
    __shared__ unsigned int lcur[NCOARSE];    // 2 KB
    __shared__ unsigned int gdst[NCOARSE];    // 2 KB
    __shared__ unsigned int partial[256];     // 1 KB

    int tid = threadIdx.x;
    int base = blockIdx.x * TILE_A;
    int count = n - base;
    if (count > TILE_A) count = TILE_A;

    for (int i = tid; i < NCOARSE; i += 256) hist[i] = 0;
    __syncthreads();

    // pass 1: coarse histogram
    for (int s = tid; s < count; s += 256) {
        int p = base + s;
        int bn = bin_of(pos[3 * p + 0], pos[3 * p + 1], pos[3 * p + 2]);
        atomicAdd(&hist[bn >> 6], 1u);
    }
    __syncthreads();

    // scan over 512 buckets (2 per thread)
    unsigned int a0 = hist[2 * tid], a1 = hist[2 * tid + 1];
    partial[tid] = a0 + a1;
    __syncthreads();
    for (int d = 1; d < 256; d <<= 1) {
        unsigned int v = (tid >= d) ? partial[tid - d] : 0u;
        __syncthreads();
        partial[tid] += v;
        __syncthreads();
    }
    unsigned int excl = (tid == 0) ? 0u : partial[tid - 1];
    lstart[2 * tid] = excl;
    lstart[2 * tid + 1] = excl + a0;
    lcur[2 * tid] = excl;
    lcur[2 * tid + 1] = excl + a0;
    // reserve global runs (padded counters: no same-line serialization)
    gdst[2 * tid]     = a0 ? atomicAdd(&ccnt[(2 * tid) * CAPP], a0) : 0u;
    gdst[2 * tid + 1] = a1 ? atomicAdd(&ccnt[(2 * tid + 1) * CAPP], a1) : 0u;
    __syncthreads();

    // pass 2: re-read pos (L1/L2-warm), pack, LDS scatter sorted-by-bucket
    for (int s = tid; s < count; s += 256) {
        int p = base + s;
        int bn;
        u64 e = pack_particle(p, pos[3 * p + 0], pos[3 * p + 1], pos[3 * p + 2], &bn);
        unsigned int r = atomicAdd(&lcur[bn >> 6], 1u);
        stage[r] = e;
        bstage[r] = (unsigned short)bn;
    }
    __syncthreads();

    // pass 3: copy runs to global (contiguous per bucket)
    for (int s = tid; s < count; s += 256) {
        int bn = bstage[s];
        int c = bn >> 6;
        unsigned int d = gdst[c] + ((unsigned int)s - lstart[c]);
        if (d < CAP_C) {
            size_t g = (size_t)c * CAP_C + d;
            coarse[g] = stage[s];
            fine8[g] = (unsigned char)(bn & 63);
        } else {
            unsigned int o = atomicAdd(ovf_cnt, 1u);
            if (o < OVF_MAX) ovf_list[o] = (unsigned int)(stage[s] >> 42);
        }
    }
}

// ---- Phase B: fine split. One block per coarse bucket; LDS counters only;
// write region 98KB, single-writer, L2-resident; slots fill [0,cnt) so
// touched lines are fully dirtied -> write ~= payload.
__global__ void __launch_bounds__(256) fine_split_kernel(
    const u64* __restrict__ coarse, const unsigned char* __restrict__ fine8,
    const unsigned int* __restrict__ ccnt,
    u64* __restrict__ slab, unsigned int* __restrict__ cnt,
    unsigned int* __restrict__ ovf_list, unsigned int* __restrict__ ovf_cnt)
{
    __shared__ unsigned int lcnt[64];
    int b = blockIdx.x;
    int tid = threadIdx.x;
    if (tid < 64) lcnt[tid] = 0;
    __syncthreads();

    unsigned int total = ccnt[b * CAPP];
    if (total > CAP_C) total = CAP_C;
    const u64* src = coarse + (size_t)b * CAP_C;
    const unsigned char* fs = fine8 + (size_t)b * CAP_C;

    // 4-way ILP over the contiguous run
    for (unsigned int j0 = tid; j0 < total; j0 += 1024) {
        u64 e[4];
        int f[4], ok[4];
#pragma unroll
        for (int k = 0; k < 4; ++k) {
            unsigned int j = j0 + (unsigned int)k * 256u;
            ok[k] = (j < total);
            unsigned int jj = ok[k] ? j : 0;
            e[k] = src[jj];
            f[k] = fs[jj] & 63;
        }
#pragma unroll
        for (int k = 0; k < 4; ++k) {
            if (ok[k]) {
                unsigned int r = atomicAdd(&lcnt[f[k]], 1u);
                if (r < CAP) {
                    slab[(size_t)((b << 6) | f[k]) * CAP + r] = e[k];
                } else {
                    unsigned int o = atomicAdd(ovf_cnt, 1u);
                    if (o < OVF_MAX) ovf_list[o] = (unsigned int)(e[k] >> 42);
                }
            }
        }
    }
    __syncthreads();
    if (tid < 64) cnt[(b << 6) | tid] = lcnt[tid];
}

// ---- Phase C: bin-centric LDS-staged gather (R15, unchanged) ----
__global__ void __launch_bounds__(128) gather_bin_kernel(
    const float* __restrict__ grid,
    const u64* __restrict__ slab,
    const unsigned int* __restrict__ cnt,
    float* __restrict__ out)
{
    int b = (blockIdx.x & 7) * 4096 + (blockIdx.x >> 3);   // bijective, 32768=8*4096

    unsigned int c = cnt[b];
    if (c == 0) return;
    if (c > CAP) c = CAP;

    int obx = 4 * (b >> 10);
    int oby = 4 * ((b >> 5) & 31);
    int obz = 4 * (b & 31);

    const int s1 = N_GRID * 3;
    const int s0 = N_GRID * N_GRID * 3;

    __shared__ float R[648];          // [6][6][18]
    const float* gorig = grid + (long)obx * s0 + oby * s1 + obz * 3;
    int tid = threadIdx.x;
#pragma unroll
    for (int f = tid; f < 648; f += 128) {
        int row = f / 18;
        int zz = f - row * 18;
        R[f] = gorig[(row / 6) * s0 + (row % 6) * s1 + zz];
    }
    __syncthreads();

    const float qs = 1.0f / 4096.0f;
    const u64* sb = slab + (size_t)b * CAP;
    for (unsigned int j = tid; j < c; j += 128) {
        u64 e = sb[j];
        int lzq = (int)(e & 4095u);
        int lyq = (int)((e >> 12) & 4095u);
        int lxq = (int)((e >> 24) & 4095u);
        int rz = (int)((e >> 36) & 3u);
        int ry = (int)((e >> 38) & 3u);
        int rx = (int)((e >> 40) & 3u);
        int idx = (int)(e >> 42);

        float lx = ((float)lxq + 0.5f) * qs;
        float ly = ((float)lyq + 0.5f) * qs;
        float lz = ((float)lzq + 0.5f) * qs;

        float wx[3], wy[3], wz[3];
        wx[0] = 0.5f * (1.0f - lx) * (1.0f - lx);
        wx[1] = 0.75f - (0.5f - lx) * (0.5f - lx);
        wx[2] = 0.5f * lx * lx;
        wy[0] = 0.5f * (1.0f - ly) * (1.0f - ly);
        wy[1] = 0.75f - (0.5f - ly) * (0.5f - ly);
        wy[2] = 0.5f * ly * ly;
        wz[0] = 0.5f * (1.0f - lz) * (1.0f - lz);
        wz[1] = 0.75f - (0.5f - lz) * (0.5f - lz);
        wz[2] = 0.5f * lz * lz;

        float ox = 0.0f, oy = 0.0f, oz = 0.0f;
#pragma unroll
        for (int a = 0; a < 3; ++a) {
#pragma unroll
            for (int bb = 0; bb < 3; ++bb) {
                const float* pp = &R[((rx + a) * 6 + (ry + bb)) * 18 + rz * 3];
                float wab = wx[a] * wy[bb];
                float w0 = wab * wz[0];
                float w1 = wab * wz[1];
                float w2 = wab * wz[2];
                ox += w0 * pp[0] + w1 * pp[3] + w2 * pp[6];
                oy += w0 * pp[1] + w1 * pp[4] + w2 * pp[7];
                oz += w0 * pp[2] + w1 * pp[5] + w2 * pp[8];
            }
        }

        out[3 * idx + 0] = ox;
        out[3 * idx + 1] = oy;
        out[3 * idx + 2] = oz;
    }
}

// ---- overflow: recompute from pos with IDENTICAL quantization ----
__global__ void __launch_bounds__(256) gather_ovf_kernel(
    const float* __restrict__ grid, const float* __restrict__ pos,
    const unsigned int* __restrict__ ovf_list, const unsigned int* __restrict__ ovf_cnt,
    float* __restrict__ out)
{
    unsigned int c = *ovf_cnt;
    if (c > OVF_MAX) c = OVF_MAX;
    const int s1 = N_GRID * 3;
    const int s0 = N_GRID * N_GRID * 3;
    const float qs = 1.0f / 4096.0f;
    for (unsigned int s = blockIdx.x * blockDim.x + threadIdx.x; s < c;
         s += gridDim.x * blockDim.x) {
        int p = (int)ovf_list[s];
        int bn;
        u64 e = pack_particle(p, pos[3 * p + 0], pos[3 * p + 1], pos[3 * p + 2], &bn);
        int obx = 4 * (bn >> 10);
        int oby = 4 * ((bn >> 5) & 31);
        int obz = 4 * (bn & 31);

        int lzq = (int)(e & 4095u);
        int lyq = (int)((e >> 12) & 4095u);
        int lxq = (int)((e >> 24) & 4095u);
        int rz = (int)((e >> 36) & 3u);
        int ry = (int)((e >> 38) & 3u);
        int rx = (int)((e >> 40) & 3u);
        int idx = (int)(e >> 42);

        float lx = ((float)lxq + 0.5f) * qs;
        float ly = ((float)lyq + 0.5f) * qs;
        float lz = ((float)lzq + 0.5f) * qs;

        float wx[3], wy[3], wz[3];
        wx[0] = 0.5f * (1.0f - lx) * (1.0f - lx);
        wx[1] = 0.75f - (0.5f - lx) * (0.5f - lx);
        wx[2] = 0.5f * lx * lx;
        wy[0] = 0.5f * (1.0f - ly) * (1.0f - ly);
        wy[1] = 0.75f - (0.5f - ly) * (0.5f - ly);
        wy[2] = 0.5f * ly * ly;
        wz[0] = 0.5f * (1.0f - lz) * (1.0f - lz);
        wz[1] = 0.75f - (0.5f - lz) * (0.5f - lz);
        wz[2] = 0.5f * lz * lz;

        const float* gbase = grid + (long)(obx + rx) * s0 + (oby + ry) * s1 + (obz + rz) * 3;
        float ox = 0, oy = 0, oz = 0;
#pragma unroll
        for (int a = 0; a < 3; ++a)
#pragma unroll
            for (int bb = 0; bb < 3; ++bb) {
                const float* pp = gbase + a * s0 + bb * s1;
                float wab = wx[a] * wy[bb];
                float w0 = wab * wz[0], w1 = wab * wz[1], w2 = wab * wz[2];
                ox += w0 * pp[0] + w1 * pp[3] + w2 * pp[6];
                oy += w0 * pp[1] + w1 * pp[4] + w2 * pp[7];
                oz += w0 * pp[2] + w1 * pp[5] + w2 * pp[8];
            }
        out[3 * idx + 0] = ox;
        out[3 * idx + 1] = oy;
        out[3 * idx + 2] = oz;
    }
}

// Fallback: naive per-particle gather
__global__ void __launch_bounds__(256) g2p_naive_kernel(
    const float* __restrict__ grid, const float* __restrict__ pos,
    float* __restrict__ out, int n)
{
    int i = blockIdx.x * blockDim.x + threadIdx.x;
    if (i >= n) return;
    float px = pos[3 * i + 0], py = pos[3 * i + 1], pz = pos[3 * i + 2];
    float nx = px * INV_DX, ny = py * INV_DX, nz = pz * INV_DX;
    int bx = (int)nx, by = (int)ny, bz = (int)nz;
    float lx = nx - bx, ly = ny - by, lz = nz - bz;
    float wx[3], wy[3], wz[3];
    wx[0] = 0.5f * (1.0f - lx) * (1.0f - lx);
    wx[1] = 0.75f - (0.5f - lx) * (0.5f - lx);
    wx[2] = 0.5f * lx * lx;
    wy[0] = 0.5f * (1.0f - ly) * (1.0f - ly);
    wy[1] = 0.75f - (0.5f - ly) * (0.5f - ly);
    wy[2] = 0.5f * ly * ly;
    wz[0] = 0.5f * (1.0f - lz) * (1.0f - lz);
    wz[1] = 0.75f - (0.5f - lz) * (0.5f - lz);
    wz[2] = 0.5f * lz * lz;
    const int s1 = N_GRID * 3, s0 = N_GRID * N_GRID * 3;
    const float* gbase = grid + (long)bx * s0 + by * s1 + bz * 3;
    float ox = 0, oy = 0, oz = 0;
#pragma unroll
    for (int a = 0; a < 3; ++a)
#pragma unroll
        for (int b = 0; b < 3; ++b) {
            const float* pp = gbase + a * s0 + b * s1;
            float wab = wx[a] * wy[b];
            float w0 = wab * wz[0], w1 = wab * wz[1], w2 = wab * wz[2];
            ox += w0 * pp[0] + w1 * pp[3] + w2 * pp[6];
            oy += w0 * pp[1] + w1 * pp[4] + w2 * pp[7];
            oz += w0 * pp[2] + w1 * pp[5] + w2 * pp[8];
        }
    out[3 * i + 0] = ox;
    out[3 * i + 1] = oy;
    out[3 * i + 2] = oz;
}

extern "C" void kernel_launch(void* const* d_in, const int* in_sizes, int n_in,
                              void* d_out, int out_size, void* d_ws, size_t ws_size,
                              hipStream_t stream) {
    const float* grid = (const float*)d_in[0];
    const float* pos  = (const float*)d_in[1];
    float* out        = (float*)d_out;
    int n = in_sizes[1] / 3;

    int block = 256;
    int blocks = (n + block - 1) / block;
    int nA = (n + TILE_A - 1) / TILE_A;

    // ws layout:
    // [0, 32K) ccnt (512 x 16 u32 padded) | [32K, +4) ovf_cnt | [36K, +256K) ovf_list
    // [512K, +128K) cnt | [1M, +coarse) | [+, +fine8) | [align, +slab)
    size_t ovfcnt_off = 32u << 10;
    size_t ovflist_off = 36u << 10;
    size_t cnt_off = 512u << 10;
    size_t coarse_off = 1u << 20;
    size_t coarse_bytes = (size_t)NCOARSE * CAP_C * sizeof(u64);      // 34.6 MB
    size_t fine8_off = coarse_off + coarse_bytes;
    size_t fine8_bytes = (size_t)NCOARSE * CAP_C;                     // 4.3 MB
    size_t slab_off = (fine8_off + fine8_bytes + 255) & ~(size_t)255;
    size_t slab_bytes = (size_t)NBINS * CAP * sizeof(u64);            // 50.3 MB
    size_t need = slab_off + slab_bytes;

    if (ws_size < need || n > (1 << 22)) {
        g2p_naive_kernel<<<blocks, block, 0, stream>>>(grid, pos, out, n);
        return;
    }

    unsigned int* ccnt = (unsigned int*)d_ws;
    unsigned int* ovf_cnt = (unsigned int*)((char*)d_ws + ovfcnt_off);
    unsigned int* ovf_list = (unsigned int*)((char*)d_ws + ovflist_off);
    unsigned int* cnt = (unsigned int*)((char*)d_ws + cnt_off);
    u64* coarse = (u64*)((char*)d_ws + coarse_off);
    unsigned char* fine8 = (unsigned char*)((char*)d_ws + fine8_off);
    u64* slab = (u64*)((char*)d_ws + slab_off);

    hipMemsetAsync(ccnt, 0, (size_t)NCOARSE * CAPP * sizeof(unsigned int), stream);
    hipMemsetAsync(ovf_cnt, 0, sizeof(unsigned int), stream);
    coarse_split_kernel<<<nA, block, 0, stream>>>(pos, coarse, fine8, ccnt, ovf_list, ovf_cnt, n);
    fine_split_kernel<<<NCOARSE, block, 0, stream>>>(coarse, fine8, ccnt, slab, cnt, ovf_list, ovf_cnt);
    gather_bin_kernel<<<NBINS, 128, 0, stream>>>(grid, slab, cnt, out);
    gather_ovf_kernel<<<16, block, 0, stream>>>(grid, pos, ovf_list, ovf_cnt, out);
}